// Round 3
// baseline (484.491 us; speedup 1.0000x reference)
//
#include <hip/hip_runtime.h>
#include <hip/hip_bf16.h>
#include <math.h>

// Problem constants (fixed by reference)
constexpr int T_ = 16384;
constexpr int D_ = 2048;   // hidden
constexpr int H_ = 1024;   // intermediate
constexpr int E_ = 8;

typedef __bf16 bf16x8 __attribute__((ext_vector_type(8)));
typedef float  f32x4  __attribute__((ext_vector_type(4)));

__device__ __forceinline__ int imin(int a, int b) { return a < b ? a : b; }

__device__ __forceinline__ bf16x8 cvt8(const float* p) {
    float4 u = *reinterpret_cast<const float4*>(p);
    float4 v = *reinterpret_cast<const float4*>(p + 4);
    bf16x8 r;
    r[0] = (__bf16)u.x; r[1] = (__bf16)u.y; r[2] = (__bf16)u.z; r[3] = (__bf16)u.w;
    r[4] = (__bf16)v.x; r[5] = (__bf16)v.y; r[6] = (__bf16)v.z; r[7] = (__bf16)v.w;
    return r;
}

// ============================ 256^2 8-phase GEMM ============================
// BM=BN=256, BK=64 (two 32-col k-halves), 512 threads = 8 waves (2M x 4N).
// LDS: A[2buf][2kh][256x32] + B same = 128 KiB. Per-wave C: 128x64 = acc[8][4].
// Staging: global_load_lds w=16, LDS chunk permutation chunk = r*4 + (s ^ ((r>>2)&3))
// -> wave read (16 lanes, rows r0..r0+15, fixed slot) spans 8 16B-positions x2 = free.
// Pipeline: stage k-halves of tile t+1 during tile t's 4 phases (order Ak0,Bk0,Ak1,Bk1);
// first read of a half is >=3 phases after issue -> s_waitcnt vmcnt(6) at phases 0,2.

#define BARX do { __builtin_amdgcn_sched_barrier(0); __builtin_amdgcn_s_barrier(); \
                  __builtin_amdgcn_sched_barrier(0); } while (0)
#define VMW6 asm volatile("s_waitcnt vmcnt(6)" ::: "memory")

// stage one k-half (256 rows x 32 cols) into a 16KB LDS half-buffer
__device__ __forceinline__ void stage_half(char* lds, const __bf16* __restrict__ src,
                                           int ldK, int valid, int tid) {
#pragma unroll
    for (int i = 0; i < 2; ++i) {
        int t = i * 512 + tid;            // 0..1023 chunk id
        int r = t >> 2, slot = t & 3;
        int rc = imin(r, valid - 1);
        int sSrc = slot ^ ((r >> 2) & 3); // inverse of read-side permutation
        const char* gp = reinterpret_cast<const char*>(src)
                       + (size_t)rc * ((size_t)ldK * 2) + sSrc * 16;
        __builtin_amdgcn_global_load_lds(
            (const __attribute__((address_space(1))) void*)gp,
            (__attribute__((address_space(3))) void*)(lds + t * 16), 16, 0, 0);
    }
}

__device__ __forceinline__ bf16x8 ldh(const char* half, int row, int swz16) {
    return *reinterpret_cast<const bf16x8*>(half + row * 64 + swz16);
}

// expert lookup for BM=256 tiles
__device__ __forceinline__ bool find_expert256(const int* __restrict__ counts, int mt,
                                               int& e, int& row0, int& valid) {
    int macc = 0, start = 0;
    e = -1;
    for (int i = 0; i < E_; ++i) {
        int c = counts[i];
        int t = (c + 255) >> 8;
        if (e < 0 && mt < macc + t) {
            int lm = mt - macc;
            e = i; row0 = start + lm * 256; valid = imin(256, c - lm * 256);
        }
        macc += t; start += c;
    }
    return e >= 0;
}

template<int K_, bool FUSE>
__global__ __launch_bounds__(512, 2) void ffn_8ph(
        const __bf16* __restrict__ A, const __bf16* __restrict__ Bw,
        const int* __restrict__ counts,
        __bf16* __restrict__ hout, float* __restrict__ fout) {
    constexpr int NT = K_ / 64;
    __shared__ alignas(16) char sA[2][2][256 * 32 * 2];
    __shared__ alignas(16) char sB[2][2][256 * 32 * 2];

    int tid = threadIdx.x;
    int mt = blockIdx.x, nt = blockIdx.y;
    int e, row0, valid;
    if (!find_expert256(counts, mt, e, row0, valid)) return;

    int wid = tid >> 6, lane = tid & 63;
    int wr = wid >> 2, wc = wid & 3;            // 2M x 4N
    int frow = lane & 15;
    int swz16 = (((lane >> 4) ^ ((lane >> 2) & 3)) << 4);

    const __bf16* Ab = A  + (size_t)row0 * K_;
    const __bf16* Bb = Bw + (size_t)e * 2048 * K_ + (size_t)(nt * 256) * K_;

    f32x4 acc[8][4] = {};

    // prologue: stage tile 0 (order Ak0, Bk0, Ak1, Bk1)
    stage_half(sA[0][0], Ab,      K_, valid, tid);
    stage_half(sB[0][0], Bb,      K_, 256,   tid);
    stage_half(sA[0][1], Ab + 32, K_, valid, tid);
    stage_half(sB[0][1], Bb + 32, K_, 256,   tid);

    for (int t = 0; t < NT; ++t) {
        int c = t & 1, nc = c ^ 1;
        int t1 = (t + 1 < NT) ? t + 1 : 0;            // wrap: harmless garbage stage
        const __bf16* An = Ab + t1 * 64;
        const __bf16* Bn = Bb + t1 * 64;
        const char* a0h = sA[c][0]; const char* a1h = sA[c][1];
        const char* b0h = sB[c][0]; const char* b1h = sB[c][1];
        bf16x8 a[4], b[4];

        // ---- phase 0: kk0, m-half 0 ----
        stage_half(sA[nc][0], An, K_, valid, tid);
        VMW6;
        BARX;
#pragma unroll
        for (int m = 0; m < 4; ++m) a[m] = ldh(a0h, wr * 128 + m * 16 + frow, swz16);
#pragma unroll
        for (int n = 0; n < 4; ++n) b[n] = ldh(b0h, wc * 64 + n * 16 + frow, swz16);
        __builtin_amdgcn_s_setprio(1);
#pragma unroll
        for (int m = 0; m < 4; ++m)
#pragma unroll
            for (int n = 0; n < 4; ++n)
                acc[m][n] = __builtin_amdgcn_mfma_f32_16x16x32_bf16(a[m], b[n], acc[m][n], 0, 0, 0);
        __builtin_amdgcn_s_setprio(0);
        BARX;

        // ---- phase 1: kk0, m-half 1 (reuse b) ----
        stage_half(sB[nc][0], Bn, K_, 256, tid);
        BARX;
#pragma unroll
        for (int m = 0; m < 4; ++m) a[m] = ldh(a0h, wr * 128 + 64 + m * 16 + frow, swz16);
        __builtin_amdgcn_s_setprio(1);
#pragma unroll
        for (int m = 0; m < 4; ++m)
#pragma unroll
            for (int n = 0; n < 4; ++n)
                acc[4 + m][n] = __builtin_amdgcn_mfma_f32_16x16x32_bf16(a[m], b[n], acc[4 + m][n], 0, 0, 0);
        __builtin_amdgcn_s_setprio(0);
        BARX;

        // ---- phase 2: kk1, m-half 0 ----
        stage_half(sA[nc][1], An + 32, K_, valid, tid);
        VMW6;
        BARX;
#pragma unroll
        for (int m = 0; m < 4; ++m) a[m] = ldh(a1h, wr * 128 + m * 16 + frow, swz16);
#pragma unroll
        for (int n = 0; n < 4; ++n) b[n] = ldh(b1h, wc * 64 + n * 16 + frow, swz16);
        __builtin_amdgcn_s_setprio(1);
#pragma unroll
        for (int m = 0; m < 4; ++m)
#pragma unroll
            for (int n = 0; n < 4; ++n)
                acc[m][n] = __builtin_amdgcn_mfma_f32_16x16x32_bf16(a[m], b[n], acc[m][n], 0, 0, 0);
        __builtin_amdgcn_s_setprio(0);
        BARX;

        // ---- phase 3: kk1, m-half 1 (reuse b) ----
        stage_half(sB[nc][1], Bn + 32, K_, 256, tid);
        BARX;
#pragma unroll
        for (int m = 0; m < 4; ++m) a[m] = ldh(a1h, wr * 128 + 64 + m * 16 + frow, swz16);
        __builtin_amdgcn_s_setprio(1);
#pragma unroll
        for (int m = 0; m < 4; ++m)
#pragma unroll
            for (int n = 0; n < 4; ++n)
                acc[4 + m][n] = __builtin_amdgcn_mfma_f32_16x16x32_bf16(a[m], b[n], acc[4 + m][n], 0, 0, 0);
        __builtin_amdgcn_s_setprio(0);
        BARX;
    }
    asm volatile("s_waitcnt vmcnt(0)" ::: "memory");   // drain wrap-stage garbage loads

    // ---- epilogue ----
    int q = lane >> 4;
#pragma unroll
    for (int m = 0; m < 8; ++m) {
#pragma unroll
        for (int j = 0; j < 4; ++j) {
            int lrow = wr * 128 + m * 16 + q * 4 + j;
            if (lrow < valid) {
                size_t rg = (size_t)(row0 + lrow);
                if (FUSE) {
                    // fragment pairs (2p, 2p+1) = (w1, w3) for the same h column
#pragma unroll
                    for (int p = 0; p < 2; ++p) {
                        float c1 = acc[m][2 * p][j], c3 = acc[m][2 * p + 1][j];
                        float inner = 0.7978845608028654f * (c1 + 0.044715f * c1 * c1 * c1);
                        float g = 0.5f * c1 * (1.0f + tanhf(inner));
                        int col = nt * 128 + 32 * wc + p * 16 + frow;
                        hout[rg * H_ + col] = (__bf16)(g * c3);
                    }
                } else {
#pragma unroll
                    for (int n = 0; n < 4; ++n) {
                        int col = nt * 256 + wc * 64 + n * 16 + frow;
                        fout[rg * D_ + col] = acc[m][n][j];
                    }
                }
            }
        }
    }
}

// ---------------- conversion kernels ----------------
__global__ __launch_bounds__(256) void cvt_f32_bf16(const float* __restrict__ in,
                                                    __bf16* __restrict__ out, int n8) {
    int i = blockIdx.x * blockDim.x + threadIdx.x;
    int stride = gridDim.x * blockDim.x;
    for (; i < n8; i += stride) {
        bf16x8 v = cvt8(in + (size_t)i * 8);
        *reinterpret_cast<bf16x8*>(out + (size_t)i * 8) = v;
    }
}

// wb[e][R][d]: rows interleaved in 32-row groups: 16 w1 rows then 16 w3 rows
__global__ __launch_bounds__(256) void interleave_w1w3(const float* __restrict__ w1,
                                                       const float* __restrict__ w3,
                                                       __bf16* __restrict__ wb) {
    int R = blockIdx.x & 2047, e = blockIdx.x >> 11;
    int g = R >> 5, r5 = R & 31;
    const float* src = (r5 < 16 ? w1 : w3)
                     + ((size_t)e * H_ + g * 16 + (r5 & 15)) * D_;
    __bf16* dst = wb + ((size_t)e * 2048 + R) * D_;
    int d = threadIdx.x * 8;
    *reinterpret_cast<bf16x8*>(dst + d) = cvt8(src + d);
}

// ================= fallback: round-1 f32 path (128^2, reg-staged) =================
constexpr int BM = 128, BN = 128, BK = 64;
constexpr int MT_MAX = T_ / BM + E_;

__device__ __forceinline__ void st_lds8(char* lds, int row, int col, bf16x8 v) {
    int byte = row * (BK * 2) + ((col * 2) ^ ((row & 7) << 4));
    *reinterpret_cast<bf16x8*>(lds + byte) = v;
}
__device__ __forceinline__ bf16x8 ld_lds8(const char* lds, int row, int kbyte) {
    int byte = row * (BK * 2) + (kbyte ^ ((row & 7) << 4));
    return *reinterpret_cast<const bf16x8*>(lds + byte);
}
template<bool CLAMP>
__device__ __forceinline__ void stage_f32(char* lds, const float* __restrict__ src,
                                          int ld, int valid, int tid) {
#pragma unroll
    for (int i = 0; i < 4; ++i) {
        int chunk = i * 256 + tid;
        int row = chunk >> 3, col = (chunk & 7) * 8;
        int r = CLAMP ? imin(row, valid - 1) : row;
        st_lds8(lds, row, col, cvt8(src + (size_t)r * ld + col));
    }
}
__device__ __forceinline__ void stage_bf16(char* lds, const __bf16* __restrict__ src,
                                           int ld, int valid, int tid) {
#pragma unroll
    for (int i = 0; i < 4; ++i) {
        int chunk = i * 256 + tid;
        int row = chunk >> 3, col = (chunk & 7) * 8;
        int r = imin(row, valid - 1);
        st_lds8(lds, row, col, *reinterpret_cast<const bf16x8*>(src + (size_t)r * ld + col));
    }
}
__device__ __forceinline__ bool find_expert(const int* __restrict__ counts, int mt,
                                            int& e, int& row0, int& valid) {
    int macc = 0, start = 0;
    e = -1;
    for (int i = 0; i < E_; ++i) {
        int c = counts[i];
        int t = (c + BM - 1) >> 7;
        if (e < 0 && mt < macc + t) {
            int lm = mt - macc;
            e = i; row0 = start + lm * BM; valid = imin(BM, c - lm * BM);
        }
        macc += t; start += c;
    }
    return e >= 0;
}

__global__ __launch_bounds__(256, 2) void ffn_stage1(
        const float* __restrict__ x, const float* __restrict__ w1,
        const float* __restrict__ w3, const int* __restrict__ counts,
        __bf16* __restrict__ hbuf) {
    __shared__ alignas(16) char sA [BM * BK * 2];
    __shared__ alignas(16) char sB1[BN * BK * 2];
    __shared__ alignas(16) char sB3[BN * BK * 2];
    int tid = threadIdx.x;
    int mt = blockIdx.x, nt = blockIdx.y;
    int e, row0, valid;
    if (!find_expert(counts, mt, e, row0, valid)) return;
    int ng0 = nt * BN;
    const float* Ab  = x  + (size_t)row0 * D_;
    const float* B1b = w1 + (size_t)e * H_ * D_ + (size_t)ng0 * D_;
    const float* B3b = w3 + (size_t)e * H_ * D_ + (size_t)ng0 * D_;
    f32x4 acc1[4][4] = {}; f32x4 acc3[4][4] = {};
    int wid = tid >> 6, lane = tid & 63;
    int wr = wid >> 1, wc = wid & 1;
    int frow = lane & 15, fkb = (lane >> 4) * 16;
    for (int k0 = 0; k0 < D_; k0 += BK) {
        stage_f32<true >(sA,  Ab  + k0, D_, valid, tid);
        stage_f32<false>(sB1, B1b + k0, D_, 0, tid);
        stage_f32<false>(sB3, B3b + k0, D_, 0, tid);
        __syncthreads();
#pragma unroll
        for (int kk = 0; kk < BK; kk += 32) {
            int kb = kk * 2 + fkb;
            bf16x8 a[4], b1[4], b3[4];
#pragma unroll
            for (int m = 0; m < 4; ++m) a[m]  = ld_lds8(sA,  wr * 64 + m * 16 + frow, kb);
#pragma unroll
            for (int n = 0; n < 4; ++n) { b1[n] = ld_lds8(sB1, wc * 64 + n * 16 + frow, kb);
                                          b3[n] = ld_lds8(sB3, wc * 64 + n * 16 + frow, kb); }
#pragma unroll
            for (int m = 0; m < 4; ++m)
#pragma unroll
                for (int n = 0; n < 4; ++n) {
                    acc1[m][n] = __builtin_amdgcn_mfma_f32_16x16x32_bf16(a[m], b1[n], acc1[m][n], 0, 0, 0);
                    acc3[m][n] = __builtin_amdgcn_mfma_f32_16x16x32_bf16(a[m], b3[n], acc3[m][n], 0, 0, 0);
                }
        }
        __syncthreads();
    }
#pragma unroll
    for (int m = 0; m < 4; ++m)
#pragma unroll
        for (int j = 0; j < 4; ++j) {
            int lrow = wr * 64 + m * 16 + (lane >> 4) * 4 + j;
            if (lrow < valid) {
                size_t gro = (size_t)(row0 + lrow) * H_;
#pragma unroll
                for (int n = 0; n < 4; ++n) {
                    float c1 = acc1[m][n][j], c3 = acc3[m][n][j];
                    float inner = 0.7978845608028654f * (c1 + 0.044715f * c1 * c1 * c1);
                    float g = 0.5f * c1 * (1.0f + tanhf(inner));
                    hbuf[gro + ng0 + wc * 64 + n * 16 + (lane & 15)] = (__bf16)(g * c3);
                }
            }
        }
}

__global__ __launch_bounds__(256, 2) void ffn_stage2(
        const __bf16* __restrict__ hbuf, const float* __restrict__ w2,
        const int* __restrict__ counts, float* __restrict__ out) {
    __shared__ alignas(16) char sA[BM * BK * 2];
    __shared__ alignas(16) char sB[BN * BK * 2];
    int tid = threadIdx.x;
    int mt = blockIdx.x, nt = blockIdx.y;
    int e, row0, valid;
    if (!find_expert(counts, mt, e, row0, valid)) return;
    int ng0 = nt * BN;
    const __bf16* Ab = hbuf + (size_t)row0 * H_;
    const float*  Bb = w2 + (size_t)e * D_ * H_ + (size_t)ng0 * H_;
    f32x4 acc[4][4] = {};
    int wid = tid >> 6, lane = tid & 63;
    int wr = wid >> 1, wc = wid & 1;
    int frow = lane & 15, fkb = (lane >> 4) * 16;
    for (int k0 = 0; k0 < H_; k0 += BK) {
        stage_bf16(sA, Ab + k0, H_, valid, tid);
        stage_f32<false>(sB, Bb + k0, H_, 0, tid);
        __syncthreads();
#pragma unroll
        for (int kk = 0; kk < BK; kk += 32) {
            int kb = kk * 2 + fkb;
            bf16x8 a[4], b[4];
#pragma unroll
            for (int m = 0; m < 4; ++m) a[m] = ld_lds8(sA, wr * 64 + m * 16 + frow, kb);
#pragma unroll
            for (int n = 0; n < 4; ++n) b[n] = ld_lds8(sB, wc * 64 + n * 16 + frow, kb);
#pragma unroll
            for (int m = 0; m < 4; ++m)
#pragma unroll
                for (int n = 0; n < 4; ++n)
                    acc[m][n] = __builtin_amdgcn_mfma_f32_16x16x32_bf16(a[m], b[n], acc[m][n], 0, 0, 0);
        }
        __syncthreads();
    }
#pragma unroll
    for (int m = 0; m < 4; ++m)
#pragma unroll
        for (int j = 0; j < 4; ++j) {
            int lrow = wr * 64 + m * 16 + (lane >> 4) * 4 + j;
            if (lrow < valid) {
                size_t gro = (size_t)(row0 + lrow) * D_;
#pragma unroll
                for (int n = 0; n < 4; ++n)
                    out[gro + ng0 + wc * 64 + n * 16 + (lane & 15)] = acc[m][n][j];
            }
        }
}

extern "C" void kernel_launch(void* const* d_in, const int* in_sizes, int n_in,
                              void* d_out, int out_size, void* d_ws, size_t ws_size,
                              hipStream_t stream) {
    const float* x      = (const float*)d_in[0];
    const float* w1     = (const float*)d_in[1];
    const float* w2     = (const float*)d_in[2];
    const float* w3     = (const float*)d_in[3];
    const int*   counts = (const int*)d_in[4];
    float* out = (float*)d_out;

    const size_t XB = (size_t)T_ * D_ * 2;          // x bf16        67.1 MB
    const size_t HB = (size_t)T_ * H_ * 2;          // h bf16        33.6 MB
    const size_t WIB = (size_t)E_ * 2 * H_ * D_ * 2; // wb interleaved 67.1 MB
    const size_t W2B = (size_t)E_ * D_ * H_ * 2;    // w2 bf16       33.6 MB
    const size_t NEED = XB + HB + WIB + W2B;        // 201.3 MB

    if (ws_size >= NEED) {
        char* ws = (char*)d_ws;
        __bf16* xb   = (__bf16*)(ws);
        __bf16* hbuf = (__bf16*)(ws + XB);
        __bf16* wb   = (__bf16*)(ws + XB + HB);
        __bf16* w2b  = (__bf16*)(ws + XB + HB + WIB);

        cvt_f32_bf16<<<2048, 256, 0, stream>>>(x,  xb,  T_ * D_ / 8);
        interleave_w1w3<<<E_ * 2048, 256, 0, stream>>>(w1, w3, wb);
        cvt_f32_bf16<<<2048, 256, 0, stream>>>(w2, w2b, E_ * D_ * H_ / 8);

        dim3 g1(T_ / 256 + E_, 2048 / 256);   // 72 x 8
        ffn_8ph<D_, true ><<<g1, 512, 0, stream>>>(xb, wb, counts, hbuf, nullptr);
        dim3 g2(T_ / 256 + E_, D_ / 256);     // 72 x 8
        ffn_8ph<H_, false><<<g2, 512, 0, stream>>>(hbuf, w2b, counts, nullptr, out);
    } else {
        __bf16* hbuf = (__bf16*)d_ws;
        dim3 g1(MT_MAX, H_ / BN);
        dim3 g2(MT_MAX, D_ / BN);
        ffn_stage1<<<g1, 256, 0, stream>>>(x, w1, w3, counts, hbuf);
        ffn_stage2<<<g2, 256, 0, stream>>>(hbuf, w2, counts, out);
    }
}

// Round 4
// 479.755 us; speedup vs baseline: 1.0099x; 1.0099x over previous
//
#include <hip/hip_runtime.h>
#include <hip/hip_bf16.h>
#include <math.h>

// Problem constants (fixed by reference)
constexpr int T_ = 16384;
constexpr int D_ = 2048;   // hidden
constexpr int H_ = 1024;   // intermediate
constexpr int E_ = 8;

constexpr int BM = 256, BN = 128, BK = 64;

typedef __bf16 bf16x8 __attribute__((ext_vector_type(8)));
typedef float  f32x4  __attribute__((ext_vector_type(4)));

__device__ __forceinline__ int imin(int a, int b) { return a < b ? a : b; }

#define SCHED0 __builtin_amdgcn_sched_barrier(0)
#define BARX do { SCHED0; __builtin_amdgcn_s_barrier(); SCHED0; } while (0)

__device__ __forceinline__ bf16x8 cvt8(const float* p) {
    float4 u = *reinterpret_cast<const float4*>(p);
    float4 v = *reinterpret_cast<const float4*>(p + 4);
    bf16x8 r;
    r[0] = (__bf16)u.x; r[1] = (__bf16)u.y; r[2] = (__bf16)u.z; r[3] = (__bf16)u.w;
    r[4] = (__bf16)v.x; r[5] = (__bf16)v.y; r[6] = (__bf16)v.z; r[7] = (__bf16)v.w;
    return r;
}

// read a bf16x8 fragment from a 128B-pitch row with the PROVEN zero-conflict
// (row&7)<<4 XOR swizzle (rounds 1-2: SQ_LDS_BANK_CONFLICT == 0)
__device__ __forceinline__ bf16x8 ldsw(const char* base, int row, int kb) {
    int byte = row * 128 + (kb ^ ((row & 7) << 4));
    return *reinterpret_cast<const bf16x8*>(base + byte);
}

// stage a full K-tile via global_load_lds w=16, source pre-swizzled:
// A 256x64 bf16 (32KB, chunks 0..2047) + B 128x64 (16KB, chunks 0..1023)
template<int K_>
__device__ __forceinline__ void stage_tile(char* bufA, char* bufB,
                                           const __bf16* __restrict__ srcA,
                                           const __bf16* __restrict__ srcB,
                                           int valid, int tid) {
#pragma unroll
    for (int i = 0; i < 6; ++i) {
        int c = i * 512 + tid;               // 0..3071, wave-uniform split at 2048
        if (c < 2048) {
            int row = c >> 3, slot = c & 7;
            int rc = imin(row, valid - 1);
            int colb = (slot * 16) ^ ((row & 7) << 4);
            const char* gp = reinterpret_cast<const char*>(srcA)
                           + (size_t)rc * (K_ * 2) + colb;
            __builtin_amdgcn_global_load_lds(
                (const __attribute__((address_space(1))) void*)gp,
                (__attribute__((address_space(3))) void*)(bufA + c * 16), 16, 0, 0);
        } else {
            int c2 = c - 2048;
            int row = c2 >> 3, slot = c2 & 7;
            int colb = (slot * 16) ^ ((row & 7) << 4);
            const char* gp = reinterpret_cast<const char*>(srcB)
                           + (size_t)row * (K_ * 2) + colb;
            __builtin_amdgcn_global_load_lds(
                (const __attribute__((address_space(1))) void*)gp,
                (__attribute__((address_space(3))) void*)(bufB + c2 * 16), 16, 0, 0);
        }
    }
}

// expert lookup for BM=256 tiles
__device__ __forceinline__ bool find_expert256(const int* __restrict__ counts, int mt,
                                               int& e, int& row0, int& valid) {
    int macc = 0, start = 0;
    e = -1;
    for (int i = 0; i < E_; ++i) {
        int c = counts[i];
        int t = (c + 255) >> 8;
        if (e < 0 && mt < macc + t) {
            int lm = mt - macc;
            e = i; row0 = start + lm * 256; valid = imin(256, c - lm * 256);
        }
        macc += t; start += c;
    }
    return e >= 0;
}

// ===================== 3-deep pipelined grouped GEMM =====================
// 256x128 tile, BK=64, 8 waves (4M x 2N), per-wave 64x64 output.
// LDS: 3 K-tile buffers (A 32KB + B 16KB each) = 144KB.
// Per K-tile: vmcnt(6) [counted: only tile t+1's 6 loads stay in flight]
// + ONE barrier + stage tile t+2 + 32 MFMA.
template<int K_, bool FUSE>
__global__ __launch_bounds__(512) void ffn_pipe(
        const __bf16* __restrict__ A, const __bf16* __restrict__ Bw,
        const int* __restrict__ counts,
        __bf16* __restrict__ hout, float* __restrict__ fout) {
    constexpr int NT = K_ / BK;
    __shared__ alignas(16) char sA[3][BM * 128];   // 3 x 32KB
    __shared__ alignas(16) char sB[3][BN * 128];   // 3 x 16KB

    int tid = threadIdx.x;
    int mt = blockIdx.x, nt = blockIdx.y;
    int e, row0, valid;
    if (!find_expert256(counts, mt, e, row0, valid)) return;

    int wid = tid >> 6, lane = tid & 63;
    int wr = wid >> 1, wc = wid & 1;          // 4M x 2N
    int frow = lane & 15, q16 = (lane >> 4) * 16;

    const __bf16* Ab = A  + (size_t)row0 * K_;
    const __bf16* Bb = Bw + (size_t)e * 2048 * K_ + (size_t)(nt * BN) * K_;

    f32x4 acc[4][4] = {};

    char *a0 = sA[0], *a1 = sA[1], *a2 = sA[2];
    char *b0 = sB[0], *b1 = sB[1], *b2 = sB[2];

    // prologue: stage tiles 0 and 1 (12 loads in flight)
    stage_tile<K_>(a0, b0, Ab,      Bb,      valid, tid);
    stage_tile<K_>(a1, b1, Ab + BK, Bb + BK, valid, tid);

    for (int t = 0; t < NT; ++t) {
        // counted drain: all loads except tile t+1's 6 -> tile t complete
        if (t < NT - 1) asm volatile("s_waitcnt vmcnt(6)" ::: "memory");
        else            asm volatile("s_waitcnt vmcnt(0)" ::: "memory");
        BARX;   // all waves past tile t-1 reads AND past their own drain

        if (t + 2 < NT)
            stage_tile<K_>(a2, b2, Ab + (t + 2) * BK, Bb + (t + 2) * BK, valid, tid);

        // ---- compute tile t from a0/b0 ----
        bf16x8 bfr[4][2];
#pragma unroll
        for (int n = 0; n < 4; ++n)
#pragma unroll
            for (int k = 0; k < 2; ++k)
                bfr[n][k] = ldsw(b0, wc * 64 + n * 16 + frow, k * 64 + q16);
        bf16x8 afr[2][2];
#pragma unroll
        for (int m = 0; m < 2; ++m)
#pragma unroll
            for (int k = 0; k < 2; ++k)
                afr[m][k] = ldsw(a0, wr * 64 + m * 16 + frow, k * 64 + q16);
        __builtin_amdgcn_s_setprio(1);
#pragma unroll
        for (int m = 0; m < 2; ++m)
#pragma unroll
            for (int n = 0; n < 4; ++n)
#pragma unroll
                for (int k = 0; k < 2; ++k)
                    acc[m][n] = __builtin_amdgcn_mfma_f32_16x16x32_bf16(afr[m][k], bfr[n][k], acc[m][n], 0, 0, 0);
        __builtin_amdgcn_s_setprio(0);
#pragma unroll
        for (int m = 0; m < 2; ++m)
#pragma unroll
            for (int k = 0; k < 2; ++k)
                afr[m][k] = ldsw(a0, wr * 64 + (2 + m) * 16 + frow, k * 64 + q16);
        __builtin_amdgcn_s_setprio(1);
#pragma unroll
        for (int m = 0; m < 2; ++m)
#pragma unroll
            for (int n = 0; n < 4; ++n)
#pragma unroll
                for (int k = 0; k < 2; ++k)
                    acc[2 + m][n] = __builtin_amdgcn_mfma_f32_16x16x32_bf16(afr[m][k], bfr[n][k], acc[2 + m][n], 0, 0, 0);
        __builtin_amdgcn_s_setprio(0);

        // rotate buffers
        char* ta = a0; a0 = a1; a1 = a2; a2 = ta;
        char* tb = b0; b0 = b1; b1 = b2; b2 = tb;
    }

    // ---- epilogue ----
    int q = lane >> 4;
#pragma unroll
    for (int m = 0; m < 4; ++m)
#pragma unroll
        for (int j = 0; j < 4; ++j) {
            int lrow = wr * 64 + m * 16 + q * 4 + j;
            if (lrow < valid) {
                size_t rg = (size_t)(row0 + lrow);
                if (FUSE) {
                    // fragment pairs (2p, 2p+1) = (w1-rows, w3-rows) of interleaved wb
#pragma unroll
                    for (int p = 0; p < 2; ++p) {
                        float c1 = acc[m][2 * p][j], c3 = acc[m][2 * p + 1][j];
                        float inner = 0.7978845608028654f * (c1 + 0.044715f * c1 * c1 * c1);
                        float g = 0.5f * c1 * (1.0f + tanhf(inner));
                        int col = (nt * 4 + wc * 2 + p) * 16 + frow;
                        hout[rg * H_ + col] = (__bf16)(g * c3);
                    }
                } else {
#pragma unroll
                    for (int n = 0; n < 4; ++n) {
                        int col = nt * BN + wc * 64 + n * 16 + frow;
                        fout[rg * D_ + col] = acc[m][n][j];
                    }
                }
            }
        }
}

// ---------------- conversion kernels ----------------
__global__ __launch_bounds__(256) void cvt_f32_bf16(const float* __restrict__ in,
                                                    __bf16* __restrict__ out, int n8) {
    int i = blockIdx.x * blockDim.x + threadIdx.x;
    int stride = gridDim.x * blockDim.x;
    for (; i < n8; i += stride) {
        bf16x8 v = cvt8(in + (size_t)i * 8);
        *reinterpret_cast<bf16x8*>(out + (size_t)i * 8) = v;
    }
}

// wb[e][R][d]: rows interleaved in 32-row groups: 16 w1 rows then 16 w3 rows
__global__ __launch_bounds__(256) void interleave_w1w3(const float* __restrict__ w1,
                                                       const float* __restrict__ w3,
                                                       __bf16* __restrict__ wb) {
    int R = blockIdx.x & 2047, e = blockIdx.x >> 11;
    int g = R >> 5, r5 = R & 31;
    const float* src = (r5 < 16 ? w1 : w3)
                     + ((size_t)e * H_ + g * 16 + (r5 & 15)) * D_;
    __bf16* dst = wb + ((size_t)e * 2048 + R) * D_;
    int d = threadIdx.x * 8;
    *reinterpret_cast<bf16x8*>(dst + d) = cvt8(src + d);
}

extern "C" void kernel_launch(void* const* d_in, const int* in_sizes, int n_in,
                              void* d_out, int out_size, void* d_ws, size_t ws_size,
                              hipStream_t stream) {
    const float* x      = (const float*)d_in[0];
    const float* w1     = (const float*)d_in[1];
    const float* w2     = (const float*)d_in[2];
    const float* w3     = (const float*)d_in[3];
    const int*   counts = (const int*)d_in[4];
    float* out = (float*)d_out;

    const size_t XB  = (size_t)T_ * D_ * 2;           // x bf16         67.1 MB
    const size_t HB  = (size_t)T_ * H_ * 2;           // h bf16         33.6 MB
    const size_t WIB = (size_t)E_ * 2 * H_ * D_ * 2;  // wb interleaved 67.1 MB
    const size_t W2B = (size_t)E_ * D_ * H_ * 2;      // w2 bf16        33.6 MB

    char* ws = (char*)d_ws;
    __bf16* xb   = (__bf16*)(ws);
    __bf16* hbuf = (__bf16*)(ws + XB);
    __bf16* wb   = (__bf16*)(ws + XB + HB);
    __bf16* w2b  = (__bf16*)(ws + XB + HB + WIB);
    (void)W2B; (void)ws_size;

    cvt_f32_bf16<<<2048, 256, 0, stream>>>(x,  xb,  T_ * D_ / 8);
    interleave_w1w3<<<E_ * 2048, 256, 0, stream>>>(w1, w3, wb);
    cvt_f32_bf16<<<2048, 256, 0, stream>>>(w2, w2b, E_ * D_ * H_ / 8);

    dim3 g1(T_ / 256 + E_, 2048 / BN);   // 72 x 16
    ffn_pipe<D_, true ><<<g1, 512, 0, stream>>>(xb, wb, counts, hbuf, nullptr);
    dim3 g2(T_ / 256 + E_, D_ / BN);     // 72 x 16
    ffn_pipe<H_, false><<<g2, 512, 0, stream>>>(hbuf, w2b, counts, nullptr, out);
}

// Round 5
// 389.472 us; speedup vs baseline: 1.2440x; 1.2318x over previous
//
#include <hip/hip_runtime.h>
#include <hip/hip_bf16.h>
#include <math.h>

// Problem constants (fixed by reference)
constexpr int T_ = 16384;
constexpr int D_ = 2048;   // hidden
constexpr int H_ = 1024;   // intermediate
constexpr int E_ = 8;

constexpr int MT256 = T_ / 256 + E_;   // 72 worst-case m-tiles (BM=256)
constexpr int NTN   = 2048 / 256;      // 8 n-tiles (both stages: N = 2048)

typedef __bf16 bf16x8 __attribute__((ext_vector_type(8)));
typedef float  f32x4  __attribute__((ext_vector_type(4)));

__device__ __forceinline__ int imin(int a, int b) { return a < b ? a : b; }

#define SCHED0 __builtin_amdgcn_sched_barrier(0)
#define BARX do { SCHED0; __builtin_amdgcn_s_barrier(); SCHED0; } while (0)
#define VMCNT(n) do { asm volatile("s_waitcnt vmcnt(" #n ")" ::: "memory"); SCHED0; } while (0)

__device__ __forceinline__ bf16x8 cvt8(const float* p) {
    float4 u = *reinterpret_cast<const float4*>(p);
    float4 v = *reinterpret_cast<const float4*>(p + 4);
    bf16x8 r;
    r[0] = (__bf16)u.x; r[1] = (__bf16)u.y; r[2] = (__bf16)u.z; r[3] = (__bf16)u.w;
    r[4] = (__bf16)v.x; r[5] = (__bf16)v.y; r[6] = (__bf16)v.z; r[7] = (__bf16)v.w;
    return r;
}

// ---- K-half panel: 256 rows x 32 bf16 cols (64B/row), row-pair packed into
// 128 super-rows of 128B. byte = sr*128 + (o ^ ((sr&7)<<4)), o = (r&1)*64 + q*16.
// Per-wave b128 read: per super-row all 8 16B slots hit exactly once (XOR is a
// bijection on slots) -> same zero-conflict class as rounds 1/2/4 (measured 0).

__device__ __forceinline__ bf16x8 ldp(const char* panel, int r, int q16) {
    int sr = r >> 1;
    int o = ((r & 1) << 6) + q16;
    int byte = sr * 128 + (o ^ ((sr & 7) << 4));
    return *reinterpret_cast<const bf16x8*>(panel + byte);
}

// stage one panel (16KB) via global_load_lds w=16; LDS dest linear, global src
// pre-permuted with the inverse (involution) of the read swizzle.
// 2 instructions per wave -> vmcnt unit = 2 per panel.
template<int K_>
__device__ __forceinline__ void stage_panel(char* dst, const __bf16* __restrict__ src,
                                            int valid, int tid) {
#pragma unroll
    for (int i = 0; i < 2; ++i) {
        int c = i * 512 + tid;               // 0..1023
        int sr = c >> 3, s = c & 7;
        int o = (s ^ (sr & 7)) << 4;         // 0..112
        int r = sr * 2 + (o >> 6);
        int kb = o & 63;                     // byte offset within the 64B row
        int rc = imin(r, valid - 1);
        const char* gp = reinterpret_cast<const char*>(src)
                       + (size_t)rc * (K_ * 2) + kb;
        __builtin_amdgcn_global_load_lds(
            (const __attribute__((address_space(1))) void*)gp,
            (__attribute__((address_space(3))) void*)(dst + c * 16), 16, 0, 0);
    }
}

// expert lookup for BM=256 tiles
__device__ __forceinline__ bool find_expert256(const int* __restrict__ counts, int mt,
                                               int& e, int& row0, int& valid) {
    int macc = 0, start = 0;
    e = -1;
    for (int i = 0; i < E_; ++i) {
        int c = counts[i];
        int t = (c + 255) >> 8;
        if (e < 0 && mt < macc + t) {
            int lm = mt - macc;
            e = i; row0 = start + lm * 256; valid = imin(256, c - lm * 256);
        }
        macc += t; start += c;
    }
    return e >= 0;
}

// ===================== 256x256 4-phase/K-tile pipelined grouped GEMM =====================
// 8 waves (2M x 4N), per-wave output 128x64 (acc[8][4]).
// LDS: 2 dbuf x 4 panels (Ak0,Bk0,Ak1,Bk1) x 16KB = 128KB.
// Phase p of tile t stages panel p of tile t+1; panel first read 3-4 phases later.
// vmcnt(6) at ph0/ph2 (= 2 loads x 3 panels in flight), never 0 in the loop.
template<int K_, bool FUSE>
__global__ __launch_bounds__(512, 2) void ffn_pipe2(
        const __bf16* __restrict__ A, const __bf16* __restrict__ Bw,
        const int* __restrict__ counts,
        __bf16* __restrict__ hout, float* __restrict__ fout) {
    constexpr int NT = K_ / 64;
    __shared__ alignas(16) char sP[2][4][16384];

    int tid = threadIdx.x;
    // XCD-bijective chunked mapping, m-fastest: each XCD owns one nt panel.
    int f = (int)blockIdx.x;                  // nwg = MT256*NTN = 576, %8 == 0
    int swz = (f & 7) * (MT256 * NTN / 8) + (f >> 3);
    int mt = swz % MT256, nt = swz / MT256;

    int e, row0, valid;
    if (!find_expert256(counts, mt, e, row0, valid)) return;

    int wid = tid >> 6, lane = tid & 63;
    int wr = wid >> 2, wc = wid & 3;          // 2M x 4N
    int frow = lane & 15, q16 = (lane >> 4) << 4;

    const __bf16* Ab = A  + (size_t)row0 * K_;
    const __bf16* Bb = Bw + (size_t)e * 2048 * K_ + (size_t)(nt * 256) * K_;

    f32x4 acc[8][4] = {};

    // prologue: stage all 4 panels of tile 0 (8 loads/wave in flight)
    stage_panel<K_>(sP[0][0], Ab,      valid, tid);
    stage_panel<K_>(sP[0][1], Bb,      256,   tid);
    stage_panel<K_>(sP[0][2], Ab + 32, valid, tid);
    stage_panel<K_>(sP[0][3], Bb + 32, 256,   tid);

    for (int t = 0; t < NT; ++t) {
        int c = t & 1, nc = c ^ 1;
        int t1 = imin(t + 1, NT - 1);         // last iter: harmless refetch
        const __bf16* An = Ab + t1 * 64;
        const __bf16* Bn = Bb + t1 * 64;
        bf16x8 afr[4], bfr[4];

        // ---- phase 0: k-half 0, m-frags 0-3 ----
        stage_panel<K_>(sP[nc][0], An, valid, tid);
        VMCNT(6);                              // Ak0(t),Bk0(t) drained
        BARX;
#pragma unroll
        for (int n = 0; n < 4; ++n) bfr[n] = ldp(sP[c][1], wc * 64 + n * 16 + frow, q16);
#pragma unroll
        for (int m = 0; m < 4; ++m) afr[m] = ldp(sP[c][0], wr * 128 + m * 16 + frow, q16);
        __builtin_amdgcn_s_setprio(1);
#pragma unroll
        for (int m = 0; m < 4; ++m)
#pragma unroll
            for (int n = 0; n < 4; ++n)
                acc[m][n] = __builtin_amdgcn_mfma_f32_16x16x32_bf16(afr[m], bfr[n], acc[m][n], 0, 0, 0);
        __builtin_amdgcn_s_setprio(0);
        BARX;

        // ---- phase 1: k-half 0, m-frags 4-7 (B reused in regs) ----
        stage_panel<K_>(sP[nc][1], Bn, 256, tid);
#pragma unroll
        for (int m = 0; m < 4; ++m) afr[m] = ldp(sP[c][0], wr * 128 + (4 + m) * 16 + frow, q16);
        BARX;
        __builtin_amdgcn_s_setprio(1);
#pragma unroll
        for (int m = 0; m < 4; ++m)
#pragma unroll
            for (int n = 0; n < 4; ++n)
                acc[4 + m][n] = __builtin_amdgcn_mfma_f32_16x16x32_bf16(afr[m], bfr[n], acc[4 + m][n], 0, 0, 0);
        __builtin_amdgcn_s_setprio(0);
        BARX;

        // ---- phase 2: k-half 1, m-frags 0-3 ----
        stage_panel<K_>(sP[nc][2], An + 32, valid, tid);
        VMCNT(6);                              // Ak1(t),Bk1(t) drained
        BARX;
#pragma unroll
        for (int n = 0; n < 4; ++n) bfr[n] = ldp(sP[c][3], wc * 64 + n * 16 + frow, q16);
#pragma unroll
        for (int m = 0; m < 4; ++m) afr[m] = ldp(sP[c][2], wr * 128 + m * 16 + frow, q16);
        __builtin_amdgcn_s_setprio(1);
#pragma unroll
        for (int m = 0; m < 4; ++m)
#pragma unroll
            for (int n = 0; n < 4; ++n)
                acc[m][n] = __builtin_amdgcn_mfma_f32_16x16x32_bf16(afr[m], bfr[n], acc[m][n], 0, 0, 0);
        __builtin_amdgcn_s_setprio(0);
        BARX;

        // ---- phase 3: k-half 1, m-frags 4-7 ----
        stage_panel<K_>(sP[nc][3], Bn + 32, 256, tid);
#pragma unroll
        for (int m = 0; m < 4; ++m) afr[m] = ldp(sP[c][2], wr * 128 + (4 + m) * 16 + frow, q16);
        BARX;
        __builtin_amdgcn_s_setprio(1);
#pragma unroll
        for (int m = 0; m < 4; ++m)
#pragma unroll
            for (int n = 0; n < 4; ++n)
                acc[4 + m][n] = __builtin_amdgcn_mfma_f32_16x16x32_bf16(afr[m], bfr[n], acc[4 + m][n], 0, 0, 0);
        __builtin_amdgcn_s_setprio(0);
        BARX;
    }
    asm volatile("s_waitcnt vmcnt(0)" ::: "memory");   // drain refetch loads

    // ---- epilogue ----
    int q = lane >> 4;
#pragma unroll
    for (int m = 0; m < 8; ++m)
#pragma unroll
        for (int j = 0; j < 4; ++j) {
            int lrow = wr * 128 + m * 16 + q * 4 + j;
            if (lrow < valid) {
                size_t rg = (size_t)(row0 + lrow);
                if (FUSE) {
                    // wb rows interleaved in 32-row groups (16 w1 + 16 w3):
                    // n even -> w1 (c1), n odd -> w3 (c3), same h column.
#pragma unroll
                    for (int p = 0; p < 2; ++p) {
                        float c1 = acc[m][2 * p][j], c3 = acc[m][2 * p + 1][j];
                        float inner = 0.7978845608028654f * (c1 + 0.044715f * c1 * c1 * c1);
                        float g = 0.5f * c1 * (1.0f + tanhf(inner));
                        int col = (nt * 8 + wc * 2 + p) * 16 + frow;
                        hout[rg * H_ + col] = (__bf16)(g * c3);
                    }
                } else {
#pragma unroll
                    for (int n = 0; n < 4; ++n) {
                        int col = nt * 256 + wc * 64 + n * 16 + frow;
                        fout[rg * D_ + col] = acc[m][n][j];
                    }
                }
            }
        }
}

// ---------------- conversion kernels ----------------
__global__ __launch_bounds__(256) void cvt_f32_bf16(const float* __restrict__ in,
                                                    __bf16* __restrict__ out, int n8) {
    int i = blockIdx.x * blockDim.x + threadIdx.x;
    int stride = gridDim.x * blockDim.x;
    for (; i < n8; i += stride) {
        bf16x8 v = cvt8(in + (size_t)i * 8);
        *reinterpret_cast<bf16x8*>(out + (size_t)i * 8) = v;
    }
}

// wb[e][R][d]: rows interleaved in 32-row groups: 16 w1 rows then 16 w3 rows
__global__ __launch_bounds__(256) void interleave_w1w3(const float* __restrict__ w1,
                                                       const float* __restrict__ w3,
                                                       __bf16* __restrict__ wb) {
    int R = blockIdx.x & 2047, e = blockIdx.x >> 11;
    int g = R >> 5, r5 = R & 31;
    const float* src = (r5 < 16 ? w1 : w3)
                     + ((size_t)e * H_ + g * 16 + (r5 & 15)) * D_;
    __bf16* dst = wb + ((size_t)e * 2048 + R) * D_;
    int d = threadIdx.x * 8;
    *reinterpret_cast<bf16x8*>(dst + d) = cvt8(src + d);
}

extern "C" void kernel_launch(void* const* d_in, const int* in_sizes, int n_in,
                              void* d_out, int out_size, void* d_ws, size_t ws_size,
                              hipStream_t stream) {
    const float* x      = (const float*)d_in[0];
    const float* w1     = (const float*)d_in[1];
    const float* w2     = (const float*)d_in[2];
    const float* w3     = (const float*)d_in[3];
    const int*   counts = (const int*)d_in[4];
    float* out = (float*)d_out;

    const size_t XB  = (size_t)T_ * D_ * 2;           // x bf16         67.1 MB
    const size_t HB  = (size_t)T_ * H_ * 2;           // h bf16         33.6 MB
    const size_t WIB = (size_t)E_ * 2 * H_ * D_ * 2;  // wb interleaved 67.1 MB

    char* ws = (char*)d_ws;
    __bf16* xb   = (__bf16*)(ws);
    __bf16* hbuf = (__bf16*)(ws + XB);
    __bf16* wb   = (__bf16*)(ws + XB + HB);
    __bf16* w2b  = (__bf16*)(ws + XB + HB + WIB);
    (void)ws_size;

    cvt_f32_bf16<<<2048, 256, 0, stream>>>(x,  xb,  T_ * D_ / 8);
    interleave_w1w3<<<E_ * 2048, 256, 0, stream>>>(w1, w3, wb);
    cvt_f32_bf16<<<2048, 256, 0, stream>>>(w2, w2b, E_ * D_ * H_ / 8);

    // stage1: N = 2048 (interleaved w1/w3), K = 2048
    ffn_pipe2<D_, true ><<<MT256 * NTN, 512, 0, stream>>>(xb, wb, counts, hbuf, nullptr);
    // stage2: N = 2048 (= D), K = 1024
    ffn_pipe2<H_, false><<<MT256 * NTN, 512, 0, stream>>>(hbuf, w2b, counts, nullptr, out);
}